// Round 4
// baseline (162.409 us; speedup 1.0000x reference)
//
#include <hip/hip_runtime.h>

#define DD 64
#define HH 128
#define NN 8192
#define TT 64
#define NSTEPS 3
#define NSUB 21   // 3 * 21 = 63 output intervals

typedef float f32x4 __attribute__((ext_vector_type(4)));
typedef short s16x8 __attribute__((ext_vector_type(8)));

// RNE float -> bf16 (weights, once)
__device__ __forceinline__ unsigned short f2bf(float f) {
    unsigned int u = __float_as_uint(f);
    u = u + 0x7FFFu + ((u >> 16) & 1u);
    return (unsigned short)(u >> 16);
}
// packed float2 -> bf16x2 (hot path)
__device__ __forceinline__ unsigned int cvt_pk_bf16(float lo, float hi) {
    unsigned int r;
    asm("v_cvt_pk_bf16_f32 %0, %1, %2" : "=v"(r) : "v"(lo), "v"(hi));
    return r;
}
// Pade(5,4) tanh: |err| < 3e-4 for |x| <= 2 (args here < ~1.2)
__device__ __forceinline__ float tanh_pade(float x) {
    float x2  = x * x;
    float num = x * fmaf(x2, x2 + 105.0f, 945.0f);
    float den = fmaf(x2, fmaf(15.0f, x2, 420.0f), 945.0f);
    return num * __builtin_amdgcn_rcpf(den);
}
// Block barrier that does NOT drain vmcnt: global stores stay in flight.
__device__ __forceinline__ void lds_barrier() {
    asm volatile("s_waitcnt lgkmcnt(0)\n\ts_barrier" ::: "memory");
}
__device__ __forceinline__ void nt_store(float* p, f32x4 v) {
    __builtin_nontemporal_store(v, reinterpret_cast<f32x4*>(p));
}

extern "C" __global__ void __launch_bounds__(256, 2)
GenODE_52965536694609_kernel(const float* __restrict__ rand_e,
                             const float* __restrict__ z0_mean,
                             const float* __restrict__ z0_log_sigma,
                             const float* __restrict__ W1,
                             const float* __restrict__ b1,
                             const float* __restrict__ W2,
                             const float* __restrict__ b2,
                             float* __restrict__ out)
{
    __shared__ __align__(16) char  zlds[16 * 128];       // [16 r][64 d] bf16, swizzled
    __shared__ __align__(16) char  hlds[16 * 256];       // [16 r][128 j] bf16, swizzled
    __shared__ __align__(16) float b1lds[HH];
    __shared__ __align__(16) char  gbuf[2 * 3 * 4096];   // regather: 2 dbuf x 3 pts x [16 r][64 d] f32

    const int tid = threadIdx.x;
    const int w   = tid >> 6;          // wave 0..3: owns j-tiles {2w,2w+1}, d-tile w
    const int l   = tid & 63;
    const int r   = l & 15;            // draw-row within tile (MFMA N)
    const int hi  = l >> 4;            // k-group
    const unsigned swz = (unsigned)((r & 7) << 4);

    if (tid < HH) b1lds[tid] = b1[tid];

    // ---- per-wave weight fragments (registers for whole integration)
    s16x8 aW1[2][2];
    #pragma unroll
    for (int mtl = 0; mtl < 2; ++mtl)
        #pragma unroll
        for (int kc = 0; kc < 2; ++kc) {
            const float* p = W1 + (size_t)((2*w + mtl)*16 + r) * DD + kc*32 + hi*8;
            f32x4 a = *reinterpret_cast<const f32x4*>(p);
            f32x4 b = *reinterpret_cast<const f32x4*>(p + 4);
            s16x8 s;
            s[0]=(short)f2bf(a[0]); s[1]=(short)f2bf(a[1]); s[2]=(short)f2bf(a[2]); s[3]=(short)f2bf(a[3]);
            s[4]=(short)f2bf(b[0]); s[5]=(short)f2bf(b[1]); s[6]=(short)f2bf(b[2]); s[7]=(short)f2bf(b[3]);
            aW1[mtl][kc] = s;
        }
    s16x8 aW2[4];
    #pragma unroll
    for (int kc = 0; kc < 4; ++kc) {
        const float* p = W2 + (size_t)(w*16 + r) * HH + kc*32 + hi*8;
        f32x4 a = *reinterpret_cast<const f32x4*>(p);
        f32x4 b = *reinterpret_cast<const f32x4*>(p + 4);
        s16x8 s;
        s[0]=(short)f2bf(a[0]); s[1]=(short)f2bf(a[1]); s[2]=(short)f2bf(a[2]); s[3]=(short)f2bf(a[3]);
        s[4]=(short)f2bf(b[0]); s[5]=(short)f2bf(b[1]); s[6]=(short)f2bf(b[2]); s[7]=(short)f2bf(b[3]);
        aW2[kc] = s;
    }
    float b2r[4];
    #pragma unroll
    for (int g = 0; g < 4; ++g) b2r[g] = b2[w*16 + 4*hi + g];

    __syncthreads();   // b1lds ready (once)

    float* out_z0 = out;
    float* out_t  = out + (size_t)NN * DD;
    float* out_z  = out_t + TT;
    if (blockIdx.x == 0 && tid < TT) out_t[tid] = (float)tid * (1.0f / 63.0f);

    // ---- state: lane (r,hi) of wave w holds z[row][d = 16w + 4hi + g], g=0..3
    const int row  = blockIdx.x * 16 + r;
    const int dOff = 16*w + 4*hi;
    const float sigma = __expf(z0_log_sigma[0]);
    float z[4];
    {
        f32x4 e = *reinterpret_cast<const f32x4*>(rand_e + (size_t)row * DD + dOff);
        f32x4 m = *reinterpret_cast<const f32x4*>(z0_mean + dOff);
        #pragma unroll
        for (int g = 0; g < 4; ++g) z[g] = m[g] + sigma * e[g];
        f32x4 v; v[0]=z[0]; v[1]=z[1]; v[2]=z[2]; v[3]=z[3];
        nt_store(out_z0 + (size_t)row * DD + dOff, v);
        nt_store(out_z  + (size_t)row * DD + dOff, v);
    }

    // ---- regather coordinates (contiguous 1KB-per-wave store pattern)
    const int lrow  = 4*w + (l >> 4);        // block-local row this lane stores
    const int d16r  = l & 15;                // 16B chunk within the row
    const unsigned wAddr = (unsigned)(r*256 + ((((unsigned)(4*w + hi))*16) ^ swz));
    const unsigned rAddr = (unsigned)(lrow*256 + (((unsigned)d16r*16) ^ ((unsigned)(lrow & 7) << 4)));
    float* const rowPtr = out_z + (size_t)(blockIdx.x*16 + lrow) * DD + d16r*4;

    // ---- one vector-field eval: y[4] -> k[4] (4-wave cooperative)
    auto vf = [&](const float (&y)[4], float (&k)[4]) {
        uint2 zw;
        zw.x = cvt_pk_bf16(y[0], y[1]);
        zw.y = cvt_pk_bf16(y[2], y[3]);
        *reinterpret_cast<uint2*>(zlds + (((unsigned)(r*128 + 32*w + 8*hi)) ^ swz)) = zw;
        lds_barrier();
        s16x8 b1f[2];
        #pragma unroll
        for (int kc = 0; kc < 2; ++kc)
            b1f[kc] = *reinterpret_cast<const s16x8*>(zlds + (((unsigned)(r*128 + 64*kc + 16*hi)) ^ swz));
        f32x4 c1[2];
        #pragma unroll
        for (int mtl = 0; mtl < 2; ++mtl) {
            c1[mtl] = *reinterpret_cast<const f32x4*>(b1lds + (2*w + mtl)*16 + 4*hi);
            c1[mtl] = __builtin_amdgcn_mfma_f32_16x16x32_bf16(aW1[mtl][0], b1f[0], c1[mtl], 0, 0, 0);
            c1[mtl] = __builtin_amdgcn_mfma_f32_16x16x32_bf16(aW1[mtl][1], b1f[1], c1[mtl], 0, 0, 0);
        }
        #pragma unroll
        for (int mtl = 0; mtl < 2; ++mtl) {
            float p0 = tanh_pade(c1[mtl][0]);
            float p1 = tanh_pade(c1[mtl][1]);
            float p2 = tanh_pade(c1[mtl][2]);
            float p3 = tanh_pade(c1[mtl][3]);
            uint2 hw;
            hw.x = cvt_pk_bf16(p0, p1);
            hw.y = cvt_pk_bf16(p2, p3);
            *reinterpret_cast<uint2*>(hlds + (((unsigned)(r*256 + (2*w + mtl)*32 + 8*hi)) ^ swz)) = hw;
        }
        lds_barrier();
        f32x4 c2;
        c2[0] = b2r[0]; c2[1] = b2r[1]; c2[2] = b2r[2]; c2[3] = b2r[3];
        #pragma unroll
        for (int kc = 0; kc < 4; ++kc) {
            s16x8 b2f = *reinterpret_cast<const s16x8*>(hlds + (((unsigned)(r*256 + 64*kc + 16*hi)) ^ swz));
            c2 = __builtin_amdgcn_mfma_f32_16x16x32_bf16(aW2[kc], b2f, c2, 0, 0, 0);
        }
        k[0] = c2[0]; k[1] = c2[1]; k[2] = c2[2]; k[3] = c2[3];
    };

    const float hs = 1.0f / (float)NSTEPS;
    float fz[4];
    vf(z, fz);

    #pragma unroll 1
    for (int s = 0; s < NSTEPS; ++s) {
        float acc[4], y[4], k[4];
        #pragma unroll
        for (int g = 0; g < 4; ++g) {
            acc[g] = fmaf(hs * (1.0f/6.0f), fz[g], z[g]);
            y[g]   = fmaf(hs * 0.5f,        fz[g], z[g]);
        }
        vf(y, k);
        #pragma unroll
        for (int g = 0; g < 4; ++g) {
            acc[g] = fmaf(hs * (1.0f/3.0f), k[g], acc[g]);
            y[g]   = fmaf(hs * 0.5f,        k[g], z[g]);
        }
        vf(y, k);
        #pragma unroll
        for (int g = 0; g < 4; ++g) {
            acc[g] = fmaf(hs * (1.0f/3.0f), k[g], acc[g]);
            y[g]   = fmaf(hs,               k[g], z[g]);
        }
        vf(y, k);
        float zn[4], fzn[4];
        #pragma unroll
        for (int g = 0; g < 4; ++g) zn[g] = fmaf(hs * (1.0f/6.0f), k[g], acc[g]);
        vf(zn, fzn);   // FSAL: next step's k1 + Hermite right slope

        // dense output: cubic Hermite at u = m/21, routed through LDS regather
        // so each wave's global store is 1KB contiguous (fill-like pattern).
        #pragma unroll 1
        for (int grp = 0; grp < 7; ++grp) {
            const int pbase = (grp & 1) * 3;
            #pragma unroll
            for (int i = 0; i < 3; ++i) {
                const int m = grp*3 + i + 1;
                const float u  = (float)m * (1.0f / (float)NSUB);
                const float u2 = u * u, u3 = u2 * u;
                const float c_z0 = 2.0f*u3 - 3.0f*u2 + 1.0f;
                const float c_z1 = 3.0f*u2 - 2.0f*u3;
                const float c_f0 = (u3 - 2.0f*u2 + u) * hs;
                const float c_f1 = (u3 - u2) * hs;
                f32x4 v;
                #pragma unroll
                for (int g = 0; g < 4; ++g)
                    v[g] = fmaf(c_z0, z[g], fmaf(c_z1, zn[g], fmaf(c_f0, fz[g], c_f1 * fzn[g])));
                *reinterpret_cast<f32x4*>(gbuf + (unsigned)(pbase + i)*4096u + wAddr) = v;
            }
            lds_barrier();
            #pragma unroll
            for (int i = 0; i < 3; ++i) {
                const int tp = s*NSUB + grp*3 + i + 1;
                f32x4 v = *reinterpret_cast<const f32x4*>(gbuf + (unsigned)(pbase + i)*4096u + rAddr);
                nt_store(rowPtr + (size_t)tp * ((size_t)NN * DD), v);
            }
        }
        #pragma unroll
        for (int g = 0; g < 4; ++g) { z[g] = zn[g]; fz[g] = fzn[g]; }
    }
}

extern "C" void kernel_launch(void* const* d_in, const int* in_sizes, int n_in,
                              void* d_out, int out_size, void* d_ws, size_t ws_size,
                              hipStream_t stream) {
    const float* rand_e       = (const float*)d_in[0];
    const float* z0_mean      = (const float*)d_in[1];
    const float* z0_log_sigma = (const float*)d_in[2];
    const float* W1           = (const float*)d_in[3];
    const float* b1           = (const float*)d_in[4];
    const float* W2           = (const float*)d_in[5];
    const float* b2           = (const float*)d_in[6];
    float* outp               = (float*)d_out;

    hipLaunchKernelGGL(GenODE_52965536694609_kernel,
                       dim3(NN / 16), dim3(256), 0, stream,
                       rand_e, z0_mean, z0_log_sigma, W1, b1, W2, b2, outp);
}